// Round 13
// baseline (498.795 us; speedup 1.0000x reference)
//
#include <hip/hip_runtime.h>

#define BLK 256
#define WBITS 13          // idx-window = 8192 edges (32KB per ei half)
#define TILEW 8192        // k_win2 tile (entries per block)
#define IPTW 16           // 512 thr * 16 = 8192
#define W1CAP 9216        // bsort stage cap (window mean 8184, +11 sigma) = 18*512
#define NSL 18
#define STCAP 4608        // per-(step,dbkt) staging cap (mean 4092, +8 sigma)
#define MAXNW 1024
#define MAXNWB 1024
#define MAXK2 2048
#define MAXNBD 512
#define OVFN 65536
#define SENT 0xFFFFFFFFu

// ---------------- init: copy compact x (n,10) into strided h (n,16) --------
__global__ void k_init_h(const float* __restrict__ x, float* __restrict__ h, int n) {
    int total = n * 16;
    int gs = gridDim.x * blockDim.x;
    for (int i = blockIdx.x * blockDim.x + threadIdx.x; i < total; i += gs) {
        int row = i >> 4, col = i & 15;
        h[i] = (col < 10) ? x[row * 10 + col] : 0.0f;
    }
}

// ---------------- pass A: LOCAL counting sort by window, coalesced dump ----
// recs1[b*TILEW + r] = block b's entries sorted by idx>>WBITS; rec=(st<<23)|idx
// woffs[b][w] = exclusive offsets. NO global atomics, no overflow.
__global__ __launch_bounds__(512) void k_win2(const int* __restrict__ orders,
                                              int total, int epo, int NW,
                                              unsigned* __restrict__ recs1,
                                              int* __restrict__ woffs) {
    __shared__ unsigned srt[TILEW];     // 32 KB
    __shared__ int bcnt[MAXNW];
    __shared__ int lofs[MAXNW + 1];
    __shared__ int sc[512];
    int t = threadIdx.x;
    for (int i = t; i < NW; i += 512) bcnt[i] = 0;
    __syncthreads();

    int b = blockIdx.x;
    size_t base = (size_t)b * TILEW;
    int lim = (int)((size_t)total - base < TILEW ? (size_t)total - base : TILEW);
    int st0 = (int)(base / (size_t)epo);
    size_t bnd = (size_t)(st0 + 1) * (size_t)epo;  // block spans <= one boundary

    unsigned recr[IPTW]; int rr[IPTW];
    #pragma unroll
    for (int q = 0; q < IPTW; ++q) {
        int e = q * 512 + t;
        recr[q] = SENT; rr[q] = 0;
        if (e < lim) {
            size_t g = base + e;
            int idx = orders[g];
            int st = (g >= bnd) ? (st0 + 1) : st0;
            recr[q] = ((unsigned)st << 23) | (unsigned)idx;
            rr[q] = atomicAdd(&bcnt[idx >> WBITS], 1);
        }
    }
    __syncthreads();
    // exclusive scan bcnt[0..NW) -> lofs[0..NW], 2 per thread
    {
        int k0 = 2 * t;
        int v0 = (k0 < NW) ? bcnt[k0] : 0;
        int v1 = (k0 + 1 < NW) ? bcnt[k0 + 1] : 0;
        int sum = v0 + v1;
        sc[t] = sum;
        __syncthreads();
        for (int off = 1; off < 512; off <<= 1) {
            int u = (t >= off) ? sc[t - off] : 0;
            __syncthreads();
            sc[t] += u;
            __syncthreads();
        }
        int run = sc[t] - sum;
        if (k0 <= NW) lofs[k0] = run;
        if (k0 + 1 <= NW) lofs[k0 + 1] = run + v0;
    }
    __syncthreads();
    #pragma unroll
    for (int q = 0; q < IPTW; ++q) {
        if (recr[q] != SENT) {
            int idx = (int)(recr[q] & 0x7FFFFFu);
            srt[lofs[idx >> WBITS] + rr[q]] = recr[q];
        }
    }
    __syncthreads();
    unsigned* dst = recs1 + base;
    for (int r = t; r < lim; r += 512) dst[r] = srt[r];
    int* bo = woffs + (size_t)b * (NW + 1);
    for (int k = t; k <= NW; k += 512) bo[k] = lofs[k];
}

// ---------------- pass B: segmented gather -> resolve -> local sort -> dump -
__global__ __launch_bounds__(512) void k_bsort(const int* __restrict__ ei, int ne,
                                               const unsigned* __restrict__ recs1,
                                               const int* __restrict__ woffs,
                                               int NWB, int NW, int NBD, int K2,
                                               unsigned* __restrict__ recs2,
                                               int* __restrict__ boffs,
                                               int* __restrict__ ovf1_cnt,
                                               unsigned* __restrict__ ovf1) {
    __shared__ unsigned stage[W1CAP];   // 36 KB, reused as sorted output
    __shared__ int cnt2[MAXK2];
    __shared__ int lofs[MAXK2 + 1];
    __shared__ int sc[512];
    __shared__ int so0[MAXNWB];
    __shared__ int slen[MAXNWB];
    __shared__ int cursor;
    int t = threadIdx.x;
    int w = blockIdx.x;
    for (int i = t; i < K2; i += 512) cnt2[i] = 0;
    if (t == 0) cursor = 0;
    // parallel offset prefetch (woffs is L3-resident)
    for (int b = t; b < NWB; b += 512) {
        const int* bo = woffs + (size_t)b * (NW + 1) + w;
        int o0 = bo[0];
        so0[b] = o0;
        slen[b] = bo[1] - o0;
    }
    __syncthreads();

    // phase A: warp-per-segment coalesced staging
    int lane = t & 63, wid = t >> 6;
    for (int b = wid; b < NWB; b += 8) {
        int len = slen[b];
        if (len > 0) {
            int bs = 0;
            if (lane == 0) bs = atomicAdd(&cursor, len);
            bs = __shfl(bs, 0);
            const unsigned* src = recs1 + (size_t)b * TILEW + so0[b];
            for (int i = lane; i < len; i += 64) {
                int pos = bs + i;
                if (pos < W1CAP) stage[pos] = src[i];
                else { int o = atomicAdd(ovf1_cnt, 1); if (o < OVFN) ovf1[o] = src[i]; }
            }
        }
    }
    __syncthreads();
    int T = cursor; if (T > W1CAP) T = W1CAP;

    // stage -> registers (static slots)
    int recr[NSL];
    #pragma unroll
    for (int q = 0; q < NSL; ++q) {
        int r = q * 512 + t;
        recr[q] = (r < T) ? (int)stage[r] : -1;
    }
    // independent d gathers (32KB window, L1/L2-hot)
    int dv[NSL];
    #pragma unroll
    for (int q = 0; q < NSL; ++q)
        dv[q] = (recr[q] >= 0) ? ei[recr[q] & 0x7FFFFF] : 0;
    // LDS rank
    unsigned meta[NSL];
    #pragma unroll
    for (int q = 0; q < NSL; ++q) {
        meta[q] = SENT;
        if (recr[q] >= 0) {
            int st = (int)(((unsigned)recr[q]) >> 23);
            int key = st * NBD + (dv[q] >> 8);
            int rk = atomicAdd(&cnt2[key], 1);
            meta[q] = ((unsigned)dv[q] << 14) | (unsigned)rk;
        }
    }
    __syncthreads();
    // exclusive scan cnt2[0..K2) -> lofs[0..K2], 4 per thread
    {
        int v[4]; int sum = 0;
        #pragma unroll
        for (int i = 0; i < 4; ++i) {
            int k = t * 4 + i;
            v[i] = (k < K2) ? cnt2[k] : 0;
            sum += v[i];
        }
        sc[t] = sum;
        __syncthreads();
        for (int off = 1; off < 512; off <<= 1) {
            int u = (t >= off) ? sc[t - off] : 0;
            __syncthreads();
            sc[t] += u;
            __syncthreads();
        }
        int run = sc[t] - sum;
        #pragma unroll
        for (int i = 0; i < 4; ++i) {
            int k = t * 4 + i;
            if (k <= K2) lofs[k] = run;
            run += v[i];
        }
        if (t == 511) lofs[K2] = sc[511];
    }
    __syncthreads();
    // s gather + scatter into sorted order (stage aliased; all reads done)
    #pragma unroll
    for (int q = 0; q < NSL; ++q) {
        if (meta[q] != SENT) {
            int idx = recr[q] & 0x7FFFFF;
            int st  = (int)(((unsigned)recr[q]) >> 23);
            int s = ei[(size_t)ne + idx];
            int d = (int)(meta[q] >> 14);
            int rk = (int)(meta[q] & 0x3FFFu);
            int key = st * NBD + (d >> 8);
            stage[lofs[key] + rk] = ((unsigned)(d & 255) << 20) | (unsigned)s;
        }
    }
    __syncthreads();
    // coalesced dump
    unsigned* dst = recs2 + (size_t)w * W1CAP;
    for (int r = t; r < T; r += 512) dst[r] = stage[r];
    int* bo2 = boffs + (size_t)w * (K2 + 1);
    for (int k = t; k <= K2; k += 512) bo2[k] = lofs[k];
}

// ---------------- aggregate: segmented gather -> LDS sort -> register sums --
template<bool FINAL>
__global__ __launch_bounds__(512) void k_agg3(const float* __restrict__ h_cur,
                                              float* __restrict__ h_next,
                                              const int* __restrict__ boffs,
                                              const unsigned* __restrict__ recs2,
                                              int NW, int K2, int NBD, int st,
                                              const float* __restrict__ w_mp,
                                              const float* __restrict__ b_mp,
                                              const float* __restrict__ w_out,
                                              const float* __restrict__ b_out,
                                              float* __restrict__ out, int n,
                                              int* __restrict__ ovf2_cnt,
                                              int2* __restrict__ ovf2) {
    __shared__ unsigned stage[STCAP];
    __shared__ unsigned srt[STCAP];
    __shared__ int so0[MAXNW];
    __shared__ int slen[MAXNW];
    __shared__ int cnts[256];
    __shared__ int sc[256];
    __shared__ int offs[257];
    __shared__ int cursor;
    __shared__ float part[256 * 10];
    __shared__ float Wa[100], Wb[100], Bm[10];
    __shared__ float Wo[100], Bo[10];
    int t = threadIdx.x;
    if (t < 100) {
        int k = t / 10, j = t - k * 10;
        float w1 = w_mp[k * 20 + j];
        float w2 = w_mp[k * 20 + 10 + j];
        Wa[t] = w1 - w2; Wb[t] = w2;
        if (FINAL) Wo[t] = w_out[t];
    }
    if (t < 10) { Bm[t] = b_mp[t]; if (FINAL) Bo[t] = b_out[t]; }
    if (t < 256) cnts[t] = 0;
    if (t == 0) cursor = 0;
    int bkt = blockIdx.x;
    int key = st * NBD + bkt;
    // parallel offset prefetch (boffs is L3-resident)
    for (int b = t; b < NW; b += 512) {
        const int* bo = boffs + (size_t)b * (K2 + 1) + key;
        int o0 = bo[0];
        so0[b] = o0;
        slen[b] = bo[1] - o0;
    }
    __syncthreads();

    // Phase A: warp-per-segment staging + histogram
    int lane = t & 63, wid = t >> 6;
    for (int b = wid; b < NW; b += 8) {
        int len = slen[b];
        if (len > 0) {
            int bs = 0;
            if (lane == 0) bs = atomicAdd(&cursor, len);
            bs = __shfl(bs, 0);
            const unsigned* src = recs2 + (size_t)b * W1CAP + so0[b];
            for (int i = lane; i < len; i += 64) {
                unsigned rec = src[i];
                int pos = bs + i;
                if (pos < STCAP) {
                    stage[pos] = rec;
                    atomicAdd(&cnts[rec >> 20], 1);
                } else {
                    int o = atomicAdd(ovf2_cnt, 1);
                    if (o < OVFN)
                        ovf2[o] = make_int2((st << 18) | (bkt * 256 + (int)(rec >> 20)),
                                            (int)(rec & 0xFFFFFu));
                }
            }
        }
    }
    __syncthreads();
    int T = cursor; if (T > STCAP) T = STCAP;

    // exclusive scan of cnts -> offs
    if (t < 256) sc[t] = cnts[t];
    __syncthreads();
    for (int off = 1; off < 256; off <<= 1) {
        int v = (t < 256 && t >= off) ? sc[t - off] : 0;
        __syncthreads();
        if (t < 256) sc[t] += v;
        __syncthreads();
    }
    if (t < 256) offs[t + 1] = sc[t];
    if (t == 0) offs[0] = 0;
    __syncthreads();
    if (t < 256) cnts[t] = offs[t];
    __syncthreads();

    // scatter into sorted order
    for (int r = t; r < T; r += 512) {
        unsigned rec = stage[r];
        int pos = atomicAdd(&cnts[rec >> 20], 1);
        srt[pos] = rec;
    }
    __syncthreads();

    // per-node gather-sum: 2 threads per node
    int node = t & 255, half = t >> 8;
    int b0 = offs[node], m = offs[node + 1] - b0;
    float S[10] = {0,0,0,0,0,0,0,0,0,0};
    for (int p = b0 + half; p < b0 + m; p += 2) {
        int s = (int)(srt[p] & 0xFFFFFu);
        const float* pj = h_cur + (size_t)s * 16;
        float4 a0 = *(const float4*)(pj);
        float4 a1 = *(const float4*)(pj + 4);
        float2 a2 = *(const float2*)(pj + 8);
        S[0] += a0.x; S[1] += a0.y; S[2] += a0.z; S[3] += a0.w;
        S[4] += a1.x; S[5] += a1.y; S[6] += a1.z; S[7] += a1.w;
        S[8] += a2.x; S[9] += a2.y;
    }
    if (half == 1) {
        #pragma unroll
        for (int j = 0; j < 10; ++j) part[node * 10 + j] = S[j];
    }
    __syncthreads();
    if (half == 0) {
        int i = bkt * 256 + node;
        if (i < n) {
            #pragma unroll
            for (int j = 0; j < 10; ++j) S[j] += part[node * 10 + j];
            const float* pi = h_cur + (size_t)i * 16;
            float4 x0 = *(const float4*)(pi);
            float4 x1 = *(const float4*)(pi + 4);
            float2 x2 = *(const float2*)(pi + 8);
            float xi[10] = {x0.x, x0.y, x0.z, x0.w, x1.x, x1.y, x1.z, x1.w, x2.x, x2.y};
            float deg = (float)m;
            float o[10];
            #pragma unroll
            for (int k = 0; k < 10; ++k) {
                float ma = Bm[k];
                float mb = 0.0f;
                #pragma unroll
                for (int j = 0; j < 10; ++j) {
                    ma += Wa[k * 10 + j] * xi[j];
                    mb += Wb[k * 10 + j] * S[j];
                }
                o[k] = xi[k] + deg * ma + mb;
            }
            if (FINAL) {
                float q2[10];
                #pragma unroll
                for (int k = 0; k < 10; ++k) {
                    float m2 = Bo[k];
                    #pragma unroll
                    for (int j = 0; j < 10; ++j) m2 += Wo[k * 10 + j] * o[j];
                    q2[k] = m2;
                }
                float* po = out + (size_t)i * 10;
                *(float2*)(po)     = make_float2(q2[0], q2[1]);
                *(float2*)(po + 2) = make_float2(q2[2], q2[3]);
                *(float2*)(po + 4) = make_float2(q2[4], q2[5]);
                *(float2*)(po + 6) = make_float2(q2[6], q2[7]);
                *(float2*)(po + 8) = make_float2(q2[8], q2[9]);
            } else {
                float* po = h_next + (size_t)i * 16;
                *(float4*)(po)     = make_float4(o[0], o[1], o[2], o[3]);
                *(float4*)(po + 4) = make_float4(o[4], o[5], o[6], o[7]);
                *(float2*)(po + 8) = make_float2(o[8], o[9]);
            }
        }
    }
}

// ---------------- overflow fix-up (expected zero entries) -------------------
__global__ void k_fix(const float* __restrict__ h_cur, float* __restrict__ h_next,
                      const int* __restrict__ ei, int ne,
                      const int* __restrict__ ovf1_cnt, const unsigned* __restrict__ ovf1,
                      const int* __restrict__ ovf2_cnt, const int2* __restrict__ ovf2,
                      const float* __restrict__ w_mp, const float* __restrict__ b_mp,
                      int st) {
    __shared__ float Wa[100], Wb[100], Bm[10];
    int t = threadIdx.x;
    if (t < 100) {
        int k = t / 10, j = t - k * 10;
        float w1 = w_mp[k * 20 + j];
        float w2 = w_mp[k * 20 + 10 + j];
        Wa[t] = w1 - w2; Wb[t] = w2;
    }
    if (t < 10) Bm[t] = b_mp[t];
    __syncthreads();
    int c1 = *ovf1_cnt; if (c1 > OVFN) c1 = OVFN;
    int c2 = *ovf2_cnt; if (c2 > OVFN) c2 = OVFN;
    int gs = gridDim.x * blockDim.x;
    for (int i = blockIdx.x * blockDim.x + t; i < c1 + c2; i += gs) {
        int d, s;
        if (i < c1) {
            unsigned v = ovf1[i];
            if ((int)(v >> 23) != st) continue;
            int idx = (int)(v & 0x7FFFFFu);
            d = ei[idx]; s = ei[(size_t)ne + idx];
        } else {
            int2 p = ovf2[i - c1];
            if ((p.x >> 18) != st) continue;
            d = p.x & 0x3FFFF; s = p.y;
        }
        const float* pi = h_cur + (size_t)d * 16;
        const float* pj = h_cur + (size_t)s * 16;
        float xi[10], xj[10];
        #pragma unroll
        for (int j = 0; j < 10; ++j) { xi[j] = pi[j]; xj[j] = pj[j]; }
        float* po = h_next + (size_t)d * 16;
        #pragma unroll
        for (int k = 0; k < 10; ++k) {
            float m = Bm[k];
            #pragma unroll
            for (int j = 0; j < 10; ++j) m += Wa[k * 10 + j] * xi[j] + Wb[k * 10 + j] * xj[j];
            atomicAdd(po + k, m);
        }
    }
}

__global__ void k_fix_final(const float* __restrict__ h_cur, float* __restrict__ out,
                            const int* __restrict__ ei, int ne,
                            const int* __restrict__ ovf1_cnt, const unsigned* __restrict__ ovf1,
                            const int* __restrict__ ovf2_cnt, const int2* __restrict__ ovf2,
                            const float* __restrict__ w_mp, const float* __restrict__ b_mp,
                            const float* __restrict__ w_out, int st) {
    __shared__ float Wa[100], Wb[100], Bm[10], Wo[100];
    int t = threadIdx.x;
    if (t < 100) {
        int k = t / 10, j = t - k * 10;
        float w1 = w_mp[k * 20 + j];
        float w2 = w_mp[k * 20 + 10 + j];
        Wa[t] = w1 - w2; Wb[t] = w2;
        Wo[t] = w_out[t];
    }
    if (t < 10) Bm[t] = b_mp[t];
    __syncthreads();
    int c1 = *ovf1_cnt; if (c1 > OVFN) c1 = OVFN;
    int c2 = *ovf2_cnt; if (c2 > OVFN) c2 = OVFN;
    int gs = gridDim.x * blockDim.x;
    for (int i = blockIdx.x * blockDim.x + t; i < c1 + c2; i += gs) {
        int d, s;
        if (i < c1) {
            unsigned v = ovf1[i];
            if ((int)(v >> 23) != st) continue;
            int idx = (int)(v & 0x7FFFFFu);
            d = ei[idx]; s = ei[(size_t)ne + idx];
        } else {
            int2 p = ovf2[i - c1];
            if ((p.x >> 18) != st) continue;
            d = p.x & 0x3FFFF; s = p.y;
        }
        const float* pi = h_cur + (size_t)d * 16;
        const float* pj = h_cur + (size_t)s * 16;
        float xi[10], xj[10];
        #pragma unroll
        for (int j = 0; j < 10; ++j) { xi[j] = pi[j]; xj[j] = pj[j]; }
        float dm[10];
        #pragma unroll
        for (int k = 0; k < 10; ++k) {
            float m = Bm[k];
            #pragma unroll
            for (int j = 0; j < 10; ++j) m += Wa[k * 10 + j] * xi[j] + Wb[k * 10 + j] * xj[j];
            dm[k] = m;
        }
        float* po = out + (size_t)d * 10;
        #pragma unroll
        for (int q = 0; q < 10; ++q) {
            float m = 0.0f;
            #pragma unroll
            for (int k = 0; k < 10; ++k) m += Wo[q * 10 + k] * dm[k];
            atomicAdd(po + q, m);
        }
    }
}

// =================== tiny-ws atomic fallback ================================

__global__ void k_init10(const float* __restrict__ x, float* __restrict__ h, int n10) {
    int gs = gridDim.x * blockDim.x;
    for (int i = blockIdx.x * blockDim.x + threadIdx.x; i < n10; i += gs) h[i] = x[i];
}
__global__ void k_copy4(const float4* __restrict__ src, float4* __restrict__ dst, int n4) {
    int gs = gridDim.x * blockDim.x;
    for (int i = blockIdx.x * blockDim.x + threadIdx.x; i < n4; i += gs) dst[i] = src[i];
}
__global__ void k_edge_step10(const float* __restrict__ h_cur, float* __restrict__ h_next,
                              const int* __restrict__ edge_index, const int* __restrict__ order,
                              const float* __restrict__ w_mp, const float* __restrict__ b_mp,
                              int epo, int ne) {
    __shared__ float Wc[200]; __shared__ float Bc[10];
    int t = threadIdx.x;
    if (t < 200) {
        int k = t / 20, j = t - k * 20;
        float w = w_mp[t];
        Wc[t] = (j < 10) ? (w - w_mp[k * 20 + j + 10]) : w;
    }
    if (t < 10) Bc[t] = b_mp[t];
    __syncthreads();
    int gs = gridDim.x * blockDim.x;
    for (int e = blockIdx.x * blockDim.x + t; e < epo; e += gs) {
        int idx = order[e];
        int dst = edge_index[idx];
        int src = edge_index[(size_t)ne + idx];
        const float* pi = h_cur + (size_t)dst * 10;
        const float* pj = h_cur + (size_t)src * 10;
        float xi[10], xj[10];
        #pragma unroll
        for (int j = 0; j < 10; ++j) { xi[j] = pi[j]; xj[j] = pj[j]; }
        float* po = h_next + (size_t)dst * 10;
        #pragma unroll
        for (int k = 0; k < 10; ++k) {
            float m = Bc[k];
            #pragma unroll
            for (int j = 0; j < 10; ++j) m += Wc[k * 20 + j] * xi[j] + Wc[k * 20 + 10 + j] * xj[j];
            atomicAdd(po + k, m);
        }
    }
}
__global__ void k_out10(const float* __restrict__ h, const float* __restrict__ w_out,
                        const float* __restrict__ b_out, float* __restrict__ out, int n) {
    __shared__ float W[100]; __shared__ float B[10];
    int t = threadIdx.x;
    if (t < 100) W[t] = w_out[t];
    if (t < 10)  B[t] = b_out[t];
    __syncthreads();
    int gs = gridDim.x * blockDim.x;
    for (int i = blockIdx.x * blockDim.x + t; i < n; i += gs) {
        float xi[10];
        #pragma unroll
        for (int j = 0; j < 10; ++j) xi[j] = h[(size_t)i * 10 + j];
        #pragma unroll
        for (int k = 0; k < 10; ++k) {
            float m = B[k];
            #pragma unroll
            for (int j = 0; j < 10; ++j) m += W[k * 10 + j] * xi[j];
            out[(size_t)i * 10 + k] = m;
        }
    }
}

// =================== launcher ===================

extern "C" void kernel_launch(void* const* d_in, const int* in_sizes, int n_in,
                              void* d_out, int out_size, void* d_ws, size_t ws_size,
                              hipStream_t stream) {
    const float* x      = (const float*)d_in[0];
    const float* w_mp   = (const float*)d_in[1];
    const float* b_mp   = (const float*)d_in[2];
    const float* w_out  = (const float*)d_in[3];
    const float* b_out  = (const float*)d_in[4];
    const int*   edge_i = (const int*)d_in[5];
    const int*   orders = (const int*)d_in[6];

    int n  = in_sizes[0] / 10;        // 100000
    int ne = in_sizes[5] / 2;         // 6400000
    const int n_orders = 4;
    int epo = in_sizes[6] / n_orders; // 1600000
    int total = n_orders * epo;

    float* out = (float*)d_out;

    int NBD = (n + 255) >> 8;                    // 391 dst buckets
    int NW  = (ne + (1 << WBITS) - 1) >> WBITS;  // 782 idx windows
    int K2  = 4 * NBD;                           // 1564
    int NWB = (total + TILEW - 1) / TILEW;       // 782 order tiles

    // workspace layout (4B elements)
    size_t off_hA    = 0;
    size_t off_hB    = off_hA + (size_t)n * 16;
    size_t off_recs1 = off_hB + (size_t)n * 16;
    size_t off_woffs = off_recs1 + (size_t)NWB * TILEW;
    size_t off_recs2 = off_woffs + (size_t)NWB * (NW + 1);
    size_t off_boffs = off_recs2 + (size_t)NW * W1CAP;
    size_t off_ovf2  = off_boffs + (size_t)NW * (K2 + 1);
    if (off_ovf2 & 1) off_ovf2++;                            // int2 align
    size_t off_ovf1  = off_ovf2 + (size_t)2 * OVFN;
    size_t off_cnts  = off_ovf1 + OVFN;                      // [0]=ovf1, [1]=ovf2
    size_t need      = (off_cnts + 2) * 4;

    bool ok = (ws_size >= need) && (NW <= MAXNW) && (NWB <= MAXNWB) &&
              (NBD <= MAXNBD) && (K2 <= MAXK2) && (ne <= (1 << 23)) && (n < (1 << 17));

    if (!ok) {
        // tiny-ws atomic fallback (8 MB)
        float* hA = (float*)d_ws;
        float* hB = hA + (size_t)n * 10;
        int n10 = n * 10;
        hipLaunchKernelGGL(k_init10, dim3(min((n10 + BLK - 1) / BLK, 2048)), dim3(BLK), 0, stream,
                           x, hA, n10);
        int n4 = n10 / 4;
        float* cur = hA; float* nxt = hB;
        int gb_edge = min((epo + BLK - 1) / BLK, 6400);
        for (int s = 0; s < n_orders; ++s) {
            hipLaunchKernelGGL(k_copy4, dim3(min((n4 + BLK - 1) / BLK, 2048)), dim3(BLK), 0, stream,
                               (const float4*)cur, (float4*)nxt, n4);
            hipLaunchKernelGGL(k_edge_step10, dim3(gb_edge), dim3(BLK), 0, stream,
                               cur, nxt, edge_i, orders + (size_t)s * epo, w_mp, b_mp, epo, ne);
            float* t2 = cur; cur = nxt; nxt = t2;
        }
        hipLaunchKernelGGL(k_out10, dim3(min((n + BLK - 1) / BLK, 2048)), dim3(BLK), 0, stream,
                           cur, w_out, b_out, out, n);
        return;
    }

    float*    hA      = (float*)d_ws;
    float*    hB      = (float*)d_ws + off_hB;
    unsigned* recs1   = (unsigned*)d_ws + off_recs1;
    int*      woffs   = (int*)d_ws + off_woffs;
    unsigned* recs2   = (unsigned*)d_ws + off_recs2;
    int*      boffs   = (int*)d_ws + off_boffs;
    int2*     ovf2    = (int2*)((int*)d_ws + off_ovf2);
    unsigned* ovf1    = (unsigned*)d_ws + off_ovf1;
    int*      ovfcnts = (int*)d_ws + off_cnts;

    hipMemsetAsync(ovfcnts, 0, 2 * sizeof(int), stream);

    int gb_init = min((n * 16 + BLK - 1) / BLK, 2048);
    hipLaunchKernelGGL(k_init_h, dim3(gb_init), dim3(BLK), 0, stream, x, hA, n);

    hipLaunchKernelGGL(k_win2, dim3(NWB), dim3(512), 0, stream,
                       orders, total, epo, NW, recs1, woffs);

    hipLaunchKernelGGL(k_bsort, dim3(NW), dim3(512), 0, stream,
                       edge_i, ne, recs1, woffs, NWB, NW, NBD, K2,
                       recs2, boffs, ovfcnts + 0, ovf1);

    float* cur = hA; float* nxt = hB;
    for (int s = 0; s < n_orders; ++s) {
        bool fin = (s == n_orders - 1);
        if (fin) {
            hipLaunchKernelGGL((k_agg3<true>), dim3(NBD), dim3(512), 0, stream,
                               cur, nxt, boffs, recs2, NW, K2, NBD, s,
                               w_mp, b_mp, w_out, b_out, out, n,
                               ovfcnts + 1, ovf2);
            hipLaunchKernelGGL(k_fix_final, dim3(8), dim3(256), 0, stream,
                               cur, out, edge_i, ne,
                               ovfcnts + 0, ovf1, ovfcnts + 1, ovf2,
                               w_mp, b_mp, w_out, s);
        } else {
            hipLaunchKernelGGL((k_agg3<false>), dim3(NBD), dim3(512), 0, stream,
                               cur, nxt, boffs, recs2, NW, K2, NBD, s,
                               w_mp, b_mp, w_out, b_out, out, n,
                               ovfcnts + 1, ovf2);
            hipLaunchKernelGGL(k_fix, dim3(8), dim3(256), 0, stream,
                               cur, nxt, edge_i, ne,
                               ovfcnts + 0, ovf1, ovfcnts + 1, ovf2,
                               w_mp, b_mp, s);
            float* t2 = cur; cur = nxt; nxt = t2;
        }
    }
}

// Round 14
// 326.914 us; speedup vs baseline: 1.5258x; 1.5258x over previous
//
#include <hip/hip_runtime.h>

#define BLK 256
#define WBITS 13          // idx-window = 8192 edges (32KB per ei half)
#define W1CAP 9216        // per-window stream cap (mean 8184, +11 sigma) = 18*512
#define STCAP 4608        // per-(step,dbkt) staging cap (mean 4092, +8 sigma)
#define MAXNW 1024
#define MAXK2 2048
#define MAXNBD 512
#define OVFN 65536
#define IPTA 32           // k_win: 512 thr * 32 = 16384 entries/block
#define NSL 18            // k_bsort: 512 thr * 18 = 9216 = W1CAP
#define EXTN 256          // agg3 block-local spill buffer
#define SENT 0xFFFFFFFFu

// ---------------- init: copy compact x (n,10) into strided h (n,16) --------
__global__ void k_init_h(const float* __restrict__ x, float* __restrict__ h, int n) {
    int total = n * 16;
    int gs = gridDim.x * blockDim.x;
    for (int i = blockIdx.x * blockDim.x + threadIdx.x; i < total; i += gs) {
        int row = i >> 4, col = i & 15;
        h[i] = (col < 10) ? x[row * 10 + col] : 0.0f;
    }
}

// ---------------- pass A: bin order entries by idx-window (mixed-step) -----
// recs1[w][pos] = (st<<23)|idx
__global__ __launch_bounds__(512) void k_win(const int* __restrict__ orders,
                                             int total, int epo, int NW,
                                             int* __restrict__ gcnt1,
                                             unsigned* __restrict__ recs1,
                                             int* __restrict__ ovf1_cnt,
                                             unsigned* __restrict__ ovf1) {
    __shared__ int bcnt[MAXNW];
    __shared__ int gbase[MAXNW];
    int t = threadIdx.x;
    for (int i = t; i < NW; i += 512) bcnt[i] = 0;
    __syncthreads();

    size_t base = (size_t)blockIdx.x * (512 * IPTA);
    int st0 = (int)(base / (size_t)epo);
    size_t b1 = (size_t)(st0 + 1) * (size_t)epo;   // block spans <= one step boundary

    unsigned recr[IPTA]; int rr[IPTA];
    #pragma unroll
    for (int q = 0; q < IPTA; ++q) {
        size_t g = base + (size_t)q * 512 + t;
        recr[q] = SENT; rr[q] = 0;
        if (g < (size_t)total) {
            int idx = orders[g];
            int st = (g >= b1) ? (st0 + 1) : st0;
            recr[q] = ((unsigned)st << 23) | (unsigned)idx;
            rr[q] = atomicAdd(&bcnt[idx >> WBITS], 1);
        }
    }
    __syncthreads();
    for (int k = t; k < NW; k += 512) {
        int c = bcnt[k];
        gbase[k] = c ? atomicAdd(&gcnt1[k], c) : 0;
    }
    __syncthreads();
    #pragma unroll
    for (int q = 0; q < IPTA; ++q) {
        if (recr[q] != SENT) {
            int idx = (int)(recr[q] & 0x7FFFFFu);
            int key = idx >> WBITS;
            int pos = gbase[key] + rr[q];
            if (pos < W1CAP)
                recs1[(size_t)key * W1CAP + pos] = recr[q];
            else {
                int o = atomicAdd(ovf1_cnt, 1);
                if (o < OVFN) ovf1[o] = recr[q];
            }
        }
    }
}

// ---------------- pass B: resolve (d,s), LOCAL counting sort, coalesced dump
// Output: recs2[w*W1CAP ..] = block's records sorted by key=(st,d>>8);
//         blk_offs[w][k] = exclusive offsets (k in [0,K2]).
__global__ __launch_bounds__(512) void k_bsort(const int* __restrict__ ei, int ne,
                                               const int* __restrict__ gcnt1,
                                               const unsigned* __restrict__ recs1,
                                               int NW, int NBD, int K2,
                                               unsigned* __restrict__ recs2,
                                               int* __restrict__ blk_offs) {
    __shared__ unsigned srt[W1CAP];     // 36 KB
    __shared__ int cnt2[MAXK2];         // histogram (K2 used)
    __shared__ int lofs[MAXK2 + 1];     // exclusive offsets
    __shared__ int sc[512];
    int t = threadIdx.x;
    for (int i = t; i < K2; i += 512) cnt2[i] = 0;
    __syncthreads();

    int w = blockIdx.x;
    int c = gcnt1[w]; if (c > W1CAP) c = W1CAP;
    const unsigned* strm = recs1 + (size_t)w * W1CAP;

    // 1) independent stream loads
    int recr[NSL];
    #pragma unroll
    for (int q = 0; q < NSL; ++q) {
        int r = q * 512 + t;
        recr[q] = (r < c) ? (int)strm[r] : -1;
    }
    // 2) independent d gathers (32KB window, L1/L2-hot)
    int dv[NSL];
    #pragma unroll
    for (int q = 0; q < NSL; ++q)
        dv[q] = (recr[q] >= 0) ? ei[recr[q] & 0x7FFFFF] : 0;
    // 3) LDS rank; meta = (d<<14)|rk (d<2^17, rk small)
    unsigned meta[NSL];
    #pragma unroll
    for (int q = 0; q < NSL; ++q) {
        meta[q] = SENT;
        if (recr[q] >= 0) {
            int st = (int)(((unsigned)recr[q]) >> 23);
            int key = st * NBD + (dv[q] >> 8);
            int rk = atomicAdd(&cnt2[key], 1);
            meta[q] = ((unsigned)dv[q] << 14) | (unsigned)rk;
        }
    }
    __syncthreads();

    // 4) exclusive scan of cnt2[0..K2) -> lofs[0..K2]
    {
        int v[4]; int sum = 0;
        #pragma unroll
        for (int i = 0; i < 4; ++i) {
            int k = t * 4 + i;
            v[i] = (k < K2) ? cnt2[k] : 0;
            sum += v[i];
        }
        sc[t] = sum;
        __syncthreads();
        for (int off = 1; off < 512; off <<= 1) {
            int u = (t >= off) ? sc[t - off] : 0;
            __syncthreads();
            sc[t] += u;
            __syncthreads();
        }
        int run = sc[t] - sum;
        #pragma unroll
        for (int i = 0; i < 4; ++i) {
            int k = t * 4 + i;
            if (k <= K2) lofs[k] = run;
            run += v[i];
        }
        if (t == 511) lofs[K2] = sc[511];   // ensure total present
    }
    __syncthreads();

    // 5) gather s + scatter into LDS sorted order
    #pragma unroll
    for (int q = 0; q < NSL; ++q) {
        if (meta[q] != SENT) {
            int idx = recr[q] & 0x7FFFFF;
            int st  = (int)(((unsigned)recr[q]) >> 23);
            int s = ei[(size_t)ne + idx];
            int d = (int)(meta[q] >> 14);
            int rk = (int)(meta[q] & 0x3FFFu);
            int key = st * NBD + (d >> 8);
            srt[lofs[key] + rk] = ((unsigned)(d & 255) << 20) | (unsigned)s;
        }
    }
    __syncthreads();

    // 6) coalesced dump of sorted records + offsets
    unsigned* dst = recs2 + (size_t)w * W1CAP;
    for (int r = t; r < c; r += 512) dst[r] = srt[r];
    int* bo = blk_offs + (size_t)w * (K2 + 1);
    for (int k = t; k <= K2; k += 512) bo[k] = lofs[k];
}

// ---------------- aggregate: segmented gather -> LDS sort -> register sums --
// Overflow handled in-kernel: ovf1 (window-cap spill) injected; stage-cap
// spill goes to block-local extra[] (spill is provably block-local).
template<bool FINAL>
__global__ __launch_bounds__(512) void k_agg3(const float* __restrict__ h_cur,
                                              float* __restrict__ h_next,
                                              const int* __restrict__ blk_offs,
                                              const unsigned* __restrict__ recs2,
                                              const int* __restrict__ ei, int ne,
                                              int NW, int K2, int NBD, int st,
                                              const float* __restrict__ w_mp,
                                              const float* __restrict__ b_mp,
                                              const float* __restrict__ w_out,
                                              const float* __restrict__ b_out,
                                              float* __restrict__ out, int n,
                                              const int* __restrict__ ovf1_cnt,
                                              const unsigned* __restrict__ ovf1) {
    __shared__ unsigned stage[STCAP];
    __shared__ unsigned srt[STCAP];
    __shared__ unsigned extra[EXTN];
    __shared__ int ecur;
    __shared__ int cnts[256];
    __shared__ int sc[256];
    __shared__ int offs[257];
    __shared__ int cursor;
    __shared__ float part[256 * 10];
    __shared__ float Wa[100], Wb[100], Bm[10];
    __shared__ float Wo[100], Bo[10];
    int t = threadIdx.x;
    if (t < 100) {
        int k = t / 10, j = t - k * 10;
        float w1 = w_mp[k * 20 + j];
        float w2 = w_mp[k * 20 + 10 + j];
        Wa[t] = w1 - w2; Wb[t] = w2;
        if (FINAL) Wo[t] = w_out[t];
    }
    if (t < 10) { Bm[t] = b_mp[t]; if (FINAL) Bo[t] = b_out[t]; }
    if (t < 256) cnts[t] = 0;
    if (t == 0) { cursor = 0; ecur = 0; }
    __syncthreads();

    int bkt = blockIdx.x;
    int key = st * NBD + bkt;

    // Phase A: gather segments from every bin-block, stage + histogram
    for (int b = t; b < NW; b += 512) {
        const int* bo = blk_offs + (size_t)b * (K2 + 1) + key;
        int o0 = bo[0], o1 = bo[1];
        int len = o1 - o0;
        if (len > 0) {
            int base = atomicAdd(&cursor, len);
            const unsigned* src = recs2 + (size_t)b * W1CAP + o0;
            for (int i = 0; i < len; ++i) {
                unsigned rec = src[i];
                int pos = base + i;
                if (pos < STCAP) {
                    stage[pos] = rec;
                    atomicAdd(&cnts[rec >> 20], 1);
                } else {
                    int e = atomicAdd(&ecur, 1);
                    if (e < EXTN) extra[e] = rec;
                }
            }
        }
    }
    // Inject ovf1 (window-cap spill from k_win; count is ~always zero)
    {
        int c1 = *ovf1_cnt; if (c1 > OVFN) c1 = OVFN;
        for (int i = t; i < c1; i += 512) {
            unsigned v = ovf1[i];
            if ((int)(v >> 23) != st) continue;
            int idx = (int)(v & 0x7FFFFFu);
            int d = ei[idx];
            if ((d >> 8) != bkt) continue;
            int s = ei[(size_t)ne + idx];
            unsigned rec = ((unsigned)(d & 255) << 20) | (unsigned)s;
            int pos = atomicAdd(&cursor, 1);
            if (pos < STCAP) {
                stage[pos] = rec;
                atomicAdd(&cnts[rec >> 20], 1);
            } else {
                int e = atomicAdd(&ecur, 1);
                if (e < EXTN) extra[e] = rec;
            }
        }
    }
    __syncthreads();
    int T = cursor; if (T > STCAP) T = STCAP;

    // exclusive scan of cnts -> offs
    if (t < 256) sc[t] = cnts[t];
    __syncthreads();
    for (int off = 1; off < 256; off <<= 1) {
        int v = (t < 256 && t >= off) ? sc[t - off] : 0;
        __syncthreads();
        if (t < 256) sc[t] += v;
        __syncthreads();
    }
    if (t < 256) offs[t + 1] = sc[t];
    if (t == 0) offs[0] = 0;
    __syncthreads();
    if (t < 256) cnts[t] = offs[t];     // cursor per node
    __syncthreads();

    // Phase C: scatter into sorted order
    for (int r = t; r < T; r += 512) {
        unsigned rec = stage[r];
        int pos = atomicAdd(&cnts[rec >> 20], 1);
        srt[pos] = rec;
    }
    __syncthreads();

    // Phase D: per-node gather-sum, 2 threads per node
    int node = t & 255, half = t >> 8;
    int b0 = offs[node], m = offs[node + 1] - b0;
    float S[10] = {0,0,0,0,0,0,0,0,0,0};
    for (int p = b0 + half; p < b0 + m; p += 2) {
        int s = (int)(srt[p] & 0xFFFFFu);
        const float* pj = h_cur + (size_t)s * 16;
        float4 a0 = *(const float4*)(pj);
        float4 a1 = *(const float4*)(pj + 4);
        float2 a2 = *(const float2*)(pj + 8);
        S[0] += a0.x; S[1] += a0.y; S[2] += a0.z; S[3] += a0.w;
        S[4] += a1.x; S[5] += a1.y; S[6] += a1.z; S[7] += a1.w;
        S[8] += a2.x; S[9] += a2.y;
    }
    if (half == 1) {
        #pragma unroll
        for (int j = 0; j < 10; ++j) part[node * 10 + j] = S[j];
    }
    __syncthreads();
    if (half == 0) {
        int i = bkt * 256 + node;
        if (i < n) {
            #pragma unroll
            for (int j = 0; j < 10; ++j) S[j] += part[node * 10 + j];
            // fold in block-local spill records (E is ~always zero)
            int E = ecur; if (E > EXTN) E = EXTN;
            for (int p = 0; p < E; ++p) {
                unsigned rec = extra[p];
                if ((int)(rec >> 20) == node) {
                    int s = (int)(rec & 0xFFFFFu);
                    const float* pj = h_cur + (size_t)s * 16;
                    #pragma unroll
                    for (int j = 0; j < 10; ++j) S[j] += pj[j];
                    ++m;
                }
            }
            const float* pi = h_cur + (size_t)i * 16;
            float4 x0 = *(const float4*)(pi);
            float4 x1 = *(const float4*)(pi + 4);
            float2 x2 = *(const float2*)(pi + 8);
            float xi[10] = {x0.x, x0.y, x0.z, x0.w, x1.x, x1.y, x1.z, x1.w, x2.x, x2.y};
            float deg = (float)m;
            float o[10];
            #pragma unroll
            for (int k = 0; k < 10; ++k) {
                float ma = Bm[k];
                float mb = 0.0f;
                #pragma unroll
                for (int j = 0; j < 10; ++j) {
                    ma += Wa[k * 10 + j] * xi[j];
                    mb += Wb[k * 10 + j] * S[j];
                }
                o[k] = xi[k] + deg * ma + mb;
            }
            if (FINAL) {
                float q2[10];
                #pragma unroll
                for (int k = 0; k < 10; ++k) {
                    float m2 = Bo[k];
                    #pragma unroll
                    for (int j = 0; j < 10; ++j) m2 += Wo[k * 10 + j] * o[j];
                    q2[k] = m2;
                }
                float* po = out + (size_t)i * 10;
                *(float2*)(po)     = make_float2(q2[0], q2[1]);
                *(float2*)(po + 2) = make_float2(q2[2], q2[3]);
                *(float2*)(po + 4) = make_float2(q2[4], q2[5]);
                *(float2*)(po + 6) = make_float2(q2[6], q2[7]);
                *(float2*)(po + 8) = make_float2(q2[8], q2[9]);
            } else {
                float* po = h_next + (size_t)i * 16;
                *(float4*)(po)     = make_float4(o[0], o[1], o[2], o[3]);
                *(float4*)(po + 4) = make_float4(o[4], o[5], o[6], o[7]);
                *(float2*)(po + 8) = make_float2(o[8], o[9]);
            }
        }
    }
}

// =================== tiny-ws atomic fallback ================================

__global__ void k_init10(const float* __restrict__ x, float* __restrict__ h, int n10) {
    int gs = gridDim.x * blockDim.x;
    for (int i = blockIdx.x * blockDim.x + threadIdx.x; i < n10; i += gs) h[i] = x[i];
}
__global__ void k_copy4(const float4* __restrict__ src, float4* __restrict__ dst, int n4) {
    int gs = gridDim.x * blockDim.x;
    for (int i = blockIdx.x * blockDim.x + threadIdx.x; i < n4; i += gs) dst[i] = src[i];
}
__global__ void k_edge_step10(const float* __restrict__ h_cur, float* __restrict__ h_next,
                              const int* __restrict__ edge_index, const int* __restrict__ order,
                              const float* __restrict__ w_mp, const float* __restrict__ b_mp,
                              int epo, int ne) {
    __shared__ float Wc[200]; __shared__ float Bc[10];
    int t = threadIdx.x;
    if (t < 200) {
        int k = t / 20, j = t - k * 20;
        float w = w_mp[t];
        Wc[t] = (j < 10) ? (w - w_mp[k * 20 + j + 10]) : w;
    }
    if (t < 10) Bc[t] = b_mp[t];
    __syncthreads();
    int gs = gridDim.x * blockDim.x;
    for (int e = blockIdx.x * blockDim.x + t; e < epo; e += gs) {
        int idx = order[e];
        int dst = edge_index[idx];
        int src = edge_index[(size_t)ne + idx];
        const float* pi = h_cur + (size_t)dst * 10;
        const float* pj = h_cur + (size_t)src * 10;
        float xi[10], xj[10];
        #pragma unroll
        for (int j = 0; j < 10; ++j) { xi[j] = pi[j]; xj[j] = pj[j]; }
        float* po = h_next + (size_t)dst * 10;
        #pragma unroll
        for (int k = 0; k < 10; ++k) {
            float m = Bc[k];
            #pragma unroll
            for (int j = 0; j < 10; ++j) m += Wc[k * 20 + j] * xi[j] + Wc[k * 20 + 10 + j] * xj[j];
            atomicAdd(po + k, m);
        }
    }
}
__global__ void k_out10(const float* __restrict__ h, const float* __restrict__ w_out,
                        const float* __restrict__ b_out, float* __restrict__ out, int n) {
    __shared__ float W[100]; __shared__ float B[10];
    int t = threadIdx.x;
    if (t < 100) W[t] = w_out[t];
    if (t < 10)  B[t] = b_out[t];
    __syncthreads();
    int gs = gridDim.x * blockDim.x;
    for (int i = blockIdx.x * blockDim.x + t; i < n; i += gs) {
        float xi[10];
        #pragma unroll
        for (int j = 0; j < 10; ++j) xi[j] = h[(size_t)i * 10 + j];
        #pragma unroll
        for (int k = 0; k < 10; ++k) {
            float m = B[k];
            #pragma unroll
            for (int j = 0; j < 10; ++j) m += W[k * 10 + j] * xi[j];
            out[(size_t)i * 10 + k] = m;
        }
    }
}

// =================== launcher ===================

extern "C" void kernel_launch(void* const* d_in, const int* in_sizes, int n_in,
                              void* d_out, int out_size, void* d_ws, size_t ws_size,
                              hipStream_t stream) {
    const float* x      = (const float*)d_in[0];
    const float* w_mp   = (const float*)d_in[1];
    const float* b_mp   = (const float*)d_in[2];
    const float* w_out  = (const float*)d_in[3];
    const float* b_out  = (const float*)d_in[4];
    const int*   edge_i = (const int*)d_in[5];
    const int*   orders = (const int*)d_in[6];

    int n  = in_sizes[0] / 10;        // 100000
    int ne = in_sizes[5] / 2;         // 6400000
    const int n_orders = 4;
    int epo = in_sizes[6] / n_orders; // 1600000
    int total = n_orders * epo;

    float* out = (float*)d_out;

    int NBD = (n + 255) >> 8;                    // 391 dst buckets
    int NW  = (ne + (1 << WBITS) - 1) >> WBITS;  // 782 idx windows
    int K2  = 4 * NBD;                           // 1564

    // workspace layout (4B elements)
    size_t off_hA    = 0;
    size_t off_hB    = off_hA + (size_t)n * 16;
    size_t off_recs1 = off_hB + (size_t)n * 16;
    size_t off_recs2 = off_recs1 + (size_t)NW * W1CAP;
    size_t off_boffs = off_recs2 + (size_t)NW * W1CAP;
    size_t off_ovf1  = off_boffs + (size_t)NW * (K2 + 1);
    size_t off_gcnt1 = off_ovf1 + OVFN;
    size_t off_cnts  = off_gcnt1 + NW;                       // [0]=ovf1_cnt
    size_t need      = (off_cnts + 1) * 4;

    bool ok = (ws_size >= need) && (NW <= MAXNW) && (NBD <= MAXNBD) &&
              (K2 <= MAXK2) && (ne <= (1 << 23)) && (n < (1 << 17));

    if (!ok) {
        // tiny-ws atomic fallback (8 MB)
        float* hA = (float*)d_ws;
        float* hB = hA + (size_t)n * 10;
        int n10 = n * 10;
        hipLaunchKernelGGL(k_init10, dim3(min((n10 + BLK - 1) / BLK, 2048)), dim3(BLK), 0, stream,
                           x, hA, n10);
        int n4 = n10 / 4;
        float* cur = hA; float* nxt = hB;
        int gb_edge = min((epo + BLK - 1) / BLK, 6400);
        for (int s = 0; s < n_orders; ++s) {
            hipLaunchKernelGGL(k_copy4, dim3(min((n4 + BLK - 1) / BLK, 2048)), dim3(BLK), 0, stream,
                               (const float4*)cur, (float4*)nxt, n4);
            hipLaunchKernelGGL(k_edge_step10, dim3(gb_edge), dim3(BLK), 0, stream,
                               cur, nxt, edge_i, orders + (size_t)s * epo, w_mp, b_mp, epo, ne);
            float* t2 = cur; cur = nxt; nxt = t2;
        }
        hipLaunchKernelGGL(k_out10, dim3(min((n + BLK - 1) / BLK, 2048)), dim3(BLK), 0, stream,
                           cur, w_out, b_out, out, n);
        return;
    }

    float*    hA      = (float*)d_ws;
    float*    hB      = (float*)d_ws + off_hB;
    unsigned* recs1   = (unsigned*)d_ws + off_recs1;
    unsigned* recs2   = (unsigned*)d_ws + off_recs2;
    int*      boffs   = (int*)d_ws + off_boffs;
    unsigned* ovf1    = (unsigned*)d_ws + off_ovf1;
    int*      gcnt1   = (int*)d_ws + off_gcnt1;
    int*      ovfcnts = (int*)d_ws + off_cnts;

    // zero gcnt1 + ovf counter (contiguous)
    hipMemsetAsync(gcnt1, 0, ((size_t)NW + 1) * sizeof(int), stream);

    int gb_init = min((n * 16 + BLK - 1) / BLK, 2048);
    hipLaunchKernelGGL(k_init_h, dim3(gb_init), dim3(BLK), 0, stream, x, hA, n);

    int gbA = (total + 512 * IPTA - 1) / (512 * IPTA);   // 391
    hipLaunchKernelGGL(k_win, dim3(gbA), dim3(512), 0, stream,
                       orders, total, epo, NW, gcnt1, recs1, ovfcnts + 0, ovf1);

    hipLaunchKernelGGL(k_bsort, dim3(NW), dim3(512), 0, stream,
                       edge_i, ne, gcnt1, recs1, NW, NBD, K2, recs2, boffs);

    float* cur = hA; float* nxt = hB;
    for (int s = 0; s < n_orders; ++s) {
        bool fin = (s == n_orders - 1);
        if (fin) {
            hipLaunchKernelGGL((k_agg3<true>), dim3(NBD), dim3(512), 0, stream,
                               cur, nxt, boffs, recs2, edge_i, ne, NW, K2, NBD, s,
                               w_mp, b_mp, w_out, b_out, out, n,
                               ovfcnts + 0, ovf1);
        } else {
            hipLaunchKernelGGL((k_agg3<false>), dim3(NBD), dim3(512), 0, stream,
                               cur, nxt, boffs, recs2, edge_i, ne, NW, K2, NBD, s,
                               w_mp, b_mp, w_out, b_out, out, n,
                               ovfcnts + 0, ovf1);
            float* t2 = cur; cur = nxt; nxt = t2;
        }
    }
}

// Round 15
// 286.672 us; speedup vs baseline: 1.7399x; 1.1404x over previous
//
#include <hip/hip_runtime.h>

#define BLK 256
#define WBITS 13          // idx-window = 8192 edges (32KB per ei half)
#define W1CAP 9216        // per-window stream cap (mean 8184, +11 sigma) = 18*512
#define STCAP 4608        // per-(step,dbkt) staging cap (mean 4092, +8 sigma)
#define MAXNW 1024
#define MAXK2 2048
#define MAXNBD 512
#define OVFN 65536
#define IPTA 32           // k_win: 512 thr * 32 = 16384 entries/block
#define NSL 18            // k_bsort: 512 thr * 18 = 9216 = W1CAP
#define SENT 0xFFFFFFFFu

// ---------------- init: copy compact x (n,10) into strided h (n,16) --------
__global__ void k_init_h(const float* __restrict__ x, float* __restrict__ h, int n) {
    int total = n * 16;
    int gs = gridDim.x * blockDim.x;
    for (int i = blockIdx.x * blockDim.x + threadIdx.x; i < total; i += gs) {
        int row = i >> 4, col = i & 15;
        h[i] = (col < 10) ? x[row * 10 + col] : 0.0f;
    }
}

// ---------------- pass A: bin order entries by idx-window (mixed-step) -----
// recs1[w][pos] = (st<<23)|idx
__global__ __launch_bounds__(512) void k_win(const int* __restrict__ orders,
                                             int total, int epo, int NW,
                                             int* __restrict__ gcnt1,
                                             unsigned* __restrict__ recs1,
                                             int* __restrict__ ovf1_cnt,
                                             unsigned* __restrict__ ovf1) {
    __shared__ int bcnt[MAXNW];
    __shared__ int gbase[MAXNW];
    int t = threadIdx.x;
    for (int i = t; i < NW; i += 512) bcnt[i] = 0;
    __syncthreads();

    size_t base = (size_t)blockIdx.x * (512 * IPTA);
    int st0 = (int)(base / (size_t)epo);
    size_t b1 = (size_t)(st0 + 1) * (size_t)epo;   // block spans <= one step boundary

    unsigned recr[IPTA]; int rr[IPTA];
    #pragma unroll
    for (int q = 0; q < IPTA; ++q) {
        size_t g = base + (size_t)q * 512 + t;
        recr[q] = SENT; rr[q] = 0;
        if (g < (size_t)total) {
            int idx = orders[g];
            int st = (g >= b1) ? (st0 + 1) : st0;
            recr[q] = ((unsigned)st << 23) | (unsigned)idx;
            rr[q] = atomicAdd(&bcnt[idx >> WBITS], 1);
        }
    }
    __syncthreads();
    for (int k = t; k < NW; k += 512) {
        int c = bcnt[k];
        gbase[k] = c ? atomicAdd(&gcnt1[k], c) : 0;
    }
    __syncthreads();
    #pragma unroll
    for (int q = 0; q < IPTA; ++q) {
        if (recr[q] != SENT) {
            int idx = (int)(recr[q] & 0x7FFFFFu);
            int key = idx >> WBITS;
            int pos = gbase[key] + rr[q];
            if (pos < W1CAP)
                recs1[(size_t)key * W1CAP + pos] = recr[q];
            else {
                int o = atomicAdd(ovf1_cnt, 1);
                if (o < OVFN) ovf1[o] = recr[q];
            }
        }
    }
}

// ---------------- pass B: resolve (d,s), LOCAL counting sort, coalesced dump
// Output: recs2[w*W1CAP ..] = block's records sorted by key=(st,d>>8);
//         blk_offs[w][k] = exclusive offsets (k in [0,K2]).
__global__ __launch_bounds__(512) void k_bsort(const int* __restrict__ ei, int ne,
                                               const int* __restrict__ gcnt1,
                                               const unsigned* __restrict__ recs1,
                                               int NW, int NBD, int K2,
                                               unsigned* __restrict__ recs2,
                                               int* __restrict__ blk_offs) {
    __shared__ unsigned srt[W1CAP];     // 36 KB
    __shared__ int cnt2[MAXK2];         // histogram (K2 used)
    __shared__ int lofs[MAXK2 + 1];     // exclusive offsets
    __shared__ int sc[512];
    int t = threadIdx.x;
    for (int i = t; i < K2; i += 512) cnt2[i] = 0;
    __syncthreads();

    int w = blockIdx.x;
    int c = gcnt1[w]; if (c > W1CAP) c = W1CAP;
    const unsigned* strm = recs1 + (size_t)w * W1CAP;

    // 1) independent stream loads
    int recr[NSL];
    #pragma unroll
    for (int q = 0; q < NSL; ++q) {
        int r = q * 512 + t;
        recr[q] = (r < c) ? (int)strm[r] : -1;
    }
    // 2) independent d gathers (32KB window, L1/L2-hot)
    int dv[NSL];
    #pragma unroll
    for (int q = 0; q < NSL; ++q)
        dv[q] = (recr[q] >= 0) ? ei[recr[q] & 0x7FFFFF] : 0;
    // 3) LDS rank; meta = (d<<14)|rk (d<2^17, rk small)
    unsigned meta[NSL];
    #pragma unroll
    for (int q = 0; q < NSL; ++q) {
        meta[q] = SENT;
        if (recr[q] >= 0) {
            int st = (int)(((unsigned)recr[q]) >> 23);
            int key = st * NBD + (dv[q] >> 8);
            int rk = atomicAdd(&cnt2[key], 1);
            meta[q] = ((unsigned)dv[q] << 14) | (unsigned)rk;
        }
    }
    __syncthreads();

    // 4) exclusive scan of cnt2[0..K2) -> lofs[0..K2]
    {
        int v[4]; int sum = 0;
        #pragma unroll
        for (int i = 0; i < 4; ++i) {
            int k = t * 4 + i;
            v[i] = (k < K2) ? cnt2[k] : 0;
            sum += v[i];
        }
        sc[t] = sum;
        __syncthreads();
        for (int off = 1; off < 512; off <<= 1) {
            int u = (t >= off) ? sc[t - off] : 0;
            __syncthreads();
            sc[t] += u;
            __syncthreads();
        }
        int run = sc[t] - sum;
        #pragma unroll
        for (int i = 0; i < 4; ++i) {
            int k = t * 4 + i;
            if (k <= K2) lofs[k] = run;
            run += v[i];
        }
        if (t == 511) lofs[K2] = sc[511];   // ensure total present
    }
    __syncthreads();

    // 5) gather s + scatter into LDS sorted order
    #pragma unroll
    for (int q = 0; q < NSL; ++q) {
        if (meta[q] != SENT) {
            int idx = recr[q] & 0x7FFFFF;
            int st  = (int)(((unsigned)recr[q]) >> 23);
            int s = ei[(size_t)ne + idx];
            int d = (int)(meta[q] >> 14);
            int rk = (int)(meta[q] & 0x3FFFu);
            int key = st * NBD + (d >> 8);
            srt[lofs[key] + rk] = ((unsigned)(d & 255) << 20) | (unsigned)s;
        }
    }
    __syncthreads();

    // 6) coalesced dump of sorted records + offsets
    unsigned* dst = recs2 + (size_t)w * W1CAP;
    for (int r = t; r < c; r += 512) dst[r] = srt[r];
    int* bo = blk_offs + (size_t)w * (K2 + 1);
    for (int k = t; k <= K2; k += 512) bo[k] = lofs[k];
}

// ---------------- aggregate: segmented gather -> LDS sort -> register sums --
template<bool FINAL>
__global__ __launch_bounds__(512) void k_agg3(const float* __restrict__ h_cur,
                                              float* __restrict__ h_next,
                                              const int* __restrict__ blk_offs,
                                              const unsigned* __restrict__ recs2,
                                              int NW, int K2, int NBD, int st,
                                              const float* __restrict__ w_mp,
                                              const float* __restrict__ b_mp,
                                              const float* __restrict__ w_out,
                                              const float* __restrict__ b_out,
                                              float* __restrict__ out, int n,
                                              int* __restrict__ ovf2_cnt,
                                              int2* __restrict__ ovf2) {
    __shared__ unsigned stage[STCAP];
    __shared__ unsigned srt[STCAP];
    __shared__ int cnts[256];
    __shared__ int sc[256];
    __shared__ int offs[257];
    __shared__ int cursor;
    __shared__ float part[256 * 10];
    __shared__ float Wa[100], Wb[100], Bm[10];
    __shared__ float Wo[100], Bo[10];
    int t = threadIdx.x;
    if (t < 100) {
        int k = t / 10, j = t - k * 10;
        float w1 = w_mp[k * 20 + j];
        float w2 = w_mp[k * 20 + 10 + j];
        Wa[t] = w1 - w2; Wb[t] = w2;
        if (FINAL) Wo[t] = w_out[t];
    }
    if (t < 10) { Bm[t] = b_mp[t]; if (FINAL) Bo[t] = b_out[t]; }
    if (t < 256) cnts[t] = 0;
    if (t == 0) cursor = 0;
    __syncthreads();

    int bkt = blockIdx.x;
    int key = st * NBD + bkt;

    // Phase A: gather segments from every bin-block, stage + histogram
    for (int b = t; b < NW; b += 512) {
        const int* bo = blk_offs + (size_t)b * (K2 + 1) + key;
        int o0 = bo[0], o1 = bo[1];
        int len = o1 - o0;
        if (len > 0) {
            int base = atomicAdd(&cursor, len);
            const unsigned* src = recs2 + (size_t)b * W1CAP + o0;
            for (int i = 0; i < len; ++i) {
                unsigned rec = src[i];
                int pos = base + i;
                if (pos < STCAP) {
                    stage[pos] = rec;
                    atomicAdd(&cnts[rec >> 20], 1);
                } else {
                    int o = atomicAdd(ovf2_cnt, 1);
                    if (o < OVFN)
                        ovf2[o] = make_int2((st << 18) | (bkt * 256 + (int)(rec >> 20)),
                                            (int)(rec & 0xFFFFFu));
                }
            }
        }
    }
    __syncthreads();
    int T = cursor; if (T > STCAP) T = STCAP;

    // exclusive scan of cnts -> offs
    if (t < 256) sc[t] = cnts[t];
    __syncthreads();
    for (int off = 1; off < 256; off <<= 1) {
        int v = (t < 256 && t >= off) ? sc[t - off] : 0;
        __syncthreads();
        if (t < 256) sc[t] += v;
        __syncthreads();
    }
    if (t < 256) offs[t + 1] = sc[t];
    if (t == 0) offs[0] = 0;
    __syncthreads();
    if (t < 256) cnts[t] = offs[t];     // cursor per node
    __syncthreads();

    // Phase C: scatter into sorted order
    for (int r = t; r < T; r += 512) {
        unsigned rec = stage[r];
        int pos = atomicAdd(&cnts[rec >> 20], 1);
        srt[pos] = rec;
    }
    __syncthreads();

    // Phase D: per-node gather-sum, 2 threads per node
    int node = t & 255, half = t >> 8;
    int b0 = offs[node], m = offs[node + 1] - b0;
    float S[10] = {0,0,0,0,0,0,0,0,0,0};
    for (int p = b0 + half; p < b0 + m; p += 2) {
        int s = (int)(srt[p] & 0xFFFFFu);
        const float* pj = h_cur + (size_t)s * 16;
        float4 a0 = *(const float4*)(pj);
        float4 a1 = *(const float4*)(pj + 4);
        float2 a2 = *(const float2*)(pj + 8);
        S[0] += a0.x; S[1] += a0.y; S[2] += a0.z; S[3] += a0.w;
        S[4] += a1.x; S[5] += a1.y; S[6] += a1.z; S[7] += a1.w;
        S[8] += a2.x; S[9] += a2.y;
    }
    if (half == 1) {
        #pragma unroll
        for (int j = 0; j < 10; ++j) part[node * 10 + j] = S[j];
    }
    __syncthreads();
    if (half == 0) {
        int i = bkt * 256 + node;
        if (i < n) {
            #pragma unroll
            for (int j = 0; j < 10; ++j) S[j] += part[node * 10 + j];
            const float* pi = h_cur + (size_t)i * 16;
            float4 x0 = *(const float4*)(pi);
            float4 x1 = *(const float4*)(pi + 4);
            float2 x2 = *(const float2*)(pi + 8);
            float xi[10] = {x0.x, x0.y, x0.z, x0.w, x1.x, x1.y, x1.z, x1.w, x2.x, x2.y};
            float deg = (float)m;
            float o[10];
            #pragma unroll
            for (int k = 0; k < 10; ++k) {
                float ma = Bm[k];
                float mb = 0.0f;
                #pragma unroll
                for (int j = 0; j < 10; ++j) {
                    ma += Wa[k * 10 + j] * xi[j];
                    mb += Wb[k * 10 + j] * S[j];
                }
                o[k] = xi[k] + deg * ma + mb;
            }
            if (FINAL) {
                float q2[10];
                #pragma unroll
                for (int k = 0; k < 10; ++k) {
                    float m2 = Bo[k];
                    #pragma unroll
                    for (int j = 0; j < 10; ++j) m2 += Wo[k * 10 + j] * o[j];
                    q2[k] = m2;
                }
                float* po = out + (size_t)i * 10;
                *(float2*)(po)     = make_float2(q2[0], q2[1]);
                *(float2*)(po + 2) = make_float2(q2[2], q2[3]);
                *(float2*)(po + 4) = make_float2(q2[4], q2[5]);
                *(float2*)(po + 6) = make_float2(q2[6], q2[7]);
                *(float2*)(po + 8) = make_float2(q2[8], q2[9]);
            } else {
                float* po = h_next + (size_t)i * 16;
                *(float4*)(po)     = make_float4(o[0], o[1], o[2], o[3]);
                *(float4*)(po + 4) = make_float4(o[4], o[5], o[6], o[7]);
                *(float2*)(po + 8) = make_float2(o[8], o[9]);
            }
        }
    }
}

// ---------------- overflow fix-up (expected zero entries) -------------------
__global__ void k_fix(const float* __restrict__ h_cur, float* __restrict__ h_next,
                      const int* __restrict__ ei, int ne,
                      const int* __restrict__ ovf1_cnt, const unsigned* __restrict__ ovf1,
                      const int* __restrict__ ovf2_cnt, const int2* __restrict__ ovf2,
                      const float* __restrict__ w_mp, const float* __restrict__ b_mp,
                      int st) {
    __shared__ float Wa[100], Wb[100], Bm[10];
    int t = threadIdx.x;
    if (t < 100) {
        int k = t / 10, j = t - k * 10;
        float w1 = w_mp[k * 20 + j];
        float w2 = w_mp[k * 20 + 10 + j];
        Wa[t] = w1 - w2; Wb[t] = w2;
    }
    if (t < 10) Bm[t] = b_mp[t];
    __syncthreads();
    int c1 = *ovf1_cnt; if (c1 > OVFN) c1 = OVFN;
    int c2 = *ovf2_cnt; if (c2 > OVFN) c2 = OVFN;
    int gs = gridDim.x * blockDim.x;
    for (int i = blockIdx.x * blockDim.x + t; i < c1 + c2; i += gs) {
        int d, s;
        if (i < c1) {
            unsigned v = ovf1[i];
            if ((int)(v >> 23) != st) continue;
            int idx = (int)(v & 0x7FFFFFu);
            d = ei[idx]; s = ei[(size_t)ne + idx];
        } else {
            int2 p = ovf2[i - c1];
            if ((p.x >> 18) != st) continue;
            d = p.x & 0x3FFFF; s = p.y;
        }
        const float* pi = h_cur + (size_t)d * 16;
        const float* pj = h_cur + (size_t)s * 16;
        float xi[10], xj[10];
        #pragma unroll
        for (int j = 0; j < 10; ++j) { xi[j] = pi[j]; xj[j] = pj[j]; }
        float* po = h_next + (size_t)d * 16;
        #pragma unroll
        for (int k = 0; k < 10; ++k) {
            float m = Bm[k];
            #pragma unroll
            for (int j = 0; j < 10; ++j) m += Wa[k * 10 + j] * xi[j] + Wb[k * 10 + j] * xj[j];
            atomicAdd(po + k, m);
        }
    }
}

__global__ void k_fix_final(const float* __restrict__ h_cur, float* __restrict__ out,
                            const int* __restrict__ ei, int ne,
                            const int* __restrict__ ovf1_cnt, const unsigned* __restrict__ ovf1,
                            const int* __restrict__ ovf2_cnt, const int2* __restrict__ ovf2,
                            const float* __restrict__ w_mp, const float* __restrict__ b_mp,
                            const float* __restrict__ w_out, int st) {
    __shared__ float Wa[100], Wb[100], Bm[10], Wo[100];
    int t = threadIdx.x;
    if (t < 100) {
        int k = t / 10, j = t - k * 10;
        float w1 = w_mp[k * 20 + j];
        float w2 = w_mp[k * 20 + 10 + j];
        Wa[t] = w1 - w2; Wb[t] = w2;
        Wo[t] = w_out[t];
    }
    if (t < 10) Bm[t] = b_mp[t];
    __syncthreads();
    int c1 = *ovf1_cnt; if (c1 > OVFN) c1 = OVFN;
    int c2 = *ovf2_cnt; if (c2 > OVFN) c2 = OVFN;
    int gs = gridDim.x * blockDim.x;
    for (int i = blockIdx.x * blockDim.x + t; i < c1 + c2; i += gs) {
        int d, s;
        if (i < c1) {
            unsigned v = ovf1[i];
            if ((int)(v >> 23) != st) continue;
            int idx = (int)(v & 0x7FFFFFu);
            d = ei[idx]; s = ei[(size_t)ne + idx];
        } else {
            int2 p = ovf2[i - c1];
            if ((p.x >> 18) != st) continue;
            d = p.x & 0x3FFFF; s = p.y;
        }
        const float* pi = h_cur + (size_t)d * 16;
        const float* pj = h_cur + (size_t)s * 16;
        float xi[10], xj[10];
        #pragma unroll
        for (int j = 0; j < 10; ++j) { xi[j] = pi[j]; xj[j] = pj[j]; }
        float dm[10];
        #pragma unroll
        for (int k = 0; k < 10; ++k) {
            float m = Bm[k];
            #pragma unroll
            for (int j = 0; j < 10; ++j) m += Wa[k * 10 + j] * xi[j] + Wb[k * 10 + j] * xj[j];
            dm[k] = m;
        }
        float* po = out + (size_t)d * 10;
        #pragma unroll
        for (int q = 0; q < 10; ++q) {
            float m = 0.0f;
            #pragma unroll
            for (int k = 0; k < 10; ++k) m += Wo[q * 10 + k] * dm[k];
            atomicAdd(po + q, m);
        }
    }
}

// =================== tiny-ws atomic fallback ================================

__global__ void k_init10(const float* __restrict__ x, float* __restrict__ h, int n10) {
    int gs = gridDim.x * blockDim.x;
    for (int i = blockIdx.x * blockDim.x + threadIdx.x; i < n10; i += gs) h[i] = x[i];
}
__global__ void k_copy4(const float4* __restrict__ src, float4* __restrict__ dst, int n4) {
    int gs = gridDim.x * blockDim.x;
    for (int i = blockIdx.x * blockDim.x + threadIdx.x; i < n4; i += gs) dst[i] = src[i];
}
__global__ void k_edge_step10(const float* __restrict__ h_cur, float* __restrict__ h_next,
                              const int* __restrict__ edge_index, const int* __restrict__ order,
                              const float* __restrict__ w_mp, const float* __restrict__ b_mp,
                              int epo, int ne) {
    __shared__ float Wc[200]; __shared__ float Bc[10];
    int t = threadIdx.x;
    if (t < 200) {
        int k = t / 20, j = t - k * 20;
        float w = w_mp[t];
        Wc[t] = (j < 10) ? (w - w_mp[k * 20 + j + 10]) : w;
    }
    if (t < 10) Bc[t] = b_mp[t];
    __syncthreads();
    int gs = gridDim.x * blockDim.x;
    for (int e = blockIdx.x * blockDim.x + t; e < epo; e += gs) {
        int idx = order[e];
        int dst = edge_index[idx];
        int src = edge_index[(size_t)ne + idx];
        const float* pi = h_cur + (size_t)dst * 10;
        const float* pj = h_cur + (size_t)src * 10;
        float xi[10], xj[10];
        #pragma unroll
        for (int j = 0; j < 10; ++j) { xi[j] = pi[j]; xj[j] = pj[j]; }
        float* po = h_next + (size_t)dst * 10;
        #pragma unroll
        for (int k = 0; k < 10; ++k) {
            float m = Bc[k];
            #pragma unroll
            for (int j = 0; j < 10; ++j) m += Wc[k * 20 + j] * xi[j] + Wc[k * 20 + 10 + j] * xj[j];
            atomicAdd(po + k, m);
        }
    }
}
__global__ void k_out10(const float* __restrict__ h, const float* __restrict__ w_out,
                        const float* __restrict__ b_out, float* __restrict__ out, int n) {
    __shared__ float W[100]; __shared__ float B[10];
    int t = threadIdx.x;
    if (t < 100) W[t] = w_out[t];
    if (t < 10)  B[t] = b_out[t];
    __syncthreads();
    int gs = gridDim.x * blockDim.x;
    for (int i = blockIdx.x * blockDim.x + t; i < n; i += gs) {
        float xi[10];
        #pragma unroll
        for (int j = 0; j < 10; ++j) xi[j] = h[(size_t)i * 10 + j];
        #pragma unroll
        for (int k = 0; k < 10; ++k) {
            float m = B[k];
            #pragma unroll
            for (int j = 0; j < 10; ++j) m += W[k * 10 + j] * xi[j];
            out[(size_t)i * 10 + k] = m;
        }
    }
}

// =================== launcher ===================

extern "C" void kernel_launch(void* const* d_in, const int* in_sizes, int n_in,
                              void* d_out, int out_size, void* d_ws, size_t ws_size,
                              hipStream_t stream) {
    const float* x      = (const float*)d_in[0];
    const float* w_mp   = (const float*)d_in[1];
    const float* b_mp   = (const float*)d_in[2];
    const float* w_out  = (const float*)d_in[3];
    const float* b_out  = (const float*)d_in[4];
    const int*   edge_i = (const int*)d_in[5];
    const int*   orders = (const int*)d_in[6];

    int n  = in_sizes[0] / 10;        // 100000
    int ne = in_sizes[5] / 2;         // 6400000
    const int n_orders = 4;
    int epo = in_sizes[6] / n_orders; // 1600000
    int total = n_orders * epo;

    float* out = (float*)d_out;

    int NBD = (n + 255) >> 8;                    // 391 dst buckets
    int NW  = (ne + (1 << WBITS) - 1) >> WBITS;  // 782 idx windows
    int K2  = 4 * NBD;                           // 1564

    // workspace layout (4B elements)
    size_t off_hA    = 0;
    size_t off_hB    = off_hA + (size_t)n * 16;
    size_t off_recs1 = off_hB + (size_t)n * 16;
    size_t off_recs2 = off_recs1 + (size_t)NW * W1CAP;
    size_t off_boffs = off_recs2 + (size_t)NW * W1CAP;
    size_t off_ovf2  = off_boffs + (size_t)NW * (K2 + 1);
    if (off_ovf2 & 1) off_ovf2++;                            // int2 align
    size_t off_ovf1  = off_ovf2 + (size_t)2 * OVFN;
    size_t off_gcnt1 = off_ovf1 + OVFN;
    size_t off_cnts  = off_gcnt1 + NW;                       // [0]=ovf1, [1]=ovf2
    size_t need      = (off_cnts + 2) * 4;

    bool ok = (ws_size >= need) && (NW <= MAXNW) && (NBD <= MAXNBD) &&
              (K2 <= MAXK2) && (ne <= (1 << 23)) && (n < (1 << 17));

    if (!ok) {
        // tiny-ws atomic fallback (8 MB)
        float* hA = (float*)d_ws;
        float* hB = hA + (size_t)n * 10;
        int n10 = n * 10;
        hipLaunchKernelGGL(k_init10, dim3(min((n10 + BLK - 1) / BLK, 2048)), dim3(BLK), 0, stream,
                           x, hA, n10);
        int n4 = n10 / 4;
        float* cur = hA; float* nxt = hB;
        int gb_edge = min((epo + BLK - 1) / BLK, 6400);
        for (int s = 0; s < n_orders; ++s) {
            hipLaunchKernelGGL(k_copy4, dim3(min((n4 + BLK - 1) / BLK, 2048)), dim3(BLK), 0, stream,
                               (const float4*)cur, (float4*)nxt, n4);
            hipLaunchKernelGGL(k_edge_step10, dim3(gb_edge), dim3(BLK), 0, stream,
                               cur, nxt, edge_i, orders + (size_t)s * epo, w_mp, b_mp, epo, ne);
            float* t2 = cur; cur = nxt; nxt = t2;
        }
        hipLaunchKernelGGL(k_out10, dim3(min((n + BLK - 1) / BLK, 2048)), dim3(BLK), 0, stream,
                           cur, w_out, b_out, out, n);
        return;
    }

    float*    hA      = (float*)d_ws;
    float*    hB      = (float*)d_ws + off_hB;
    unsigned* recs1   = (unsigned*)d_ws + off_recs1;
    unsigned* recs2   = (unsigned*)d_ws + off_recs2;
    int*      boffs   = (int*)d_ws + off_boffs;
    int2*     ovf2    = (int2*)((int*)d_ws + off_ovf2);
    unsigned* ovf1    = (unsigned*)d_ws + off_ovf1;
    int*      gcnt1   = (int*)d_ws + off_gcnt1;
    int*      ovfcnts = (int*)d_ws + off_cnts;

    // zero gcnt1 + ovf counters (contiguous)
    hipMemsetAsync(gcnt1, 0, ((size_t)NW + 2) * sizeof(int), stream);

    int gb_init = min((n * 16 + BLK - 1) / BLK, 2048);
    hipLaunchKernelGGL(k_init_h, dim3(gb_init), dim3(BLK), 0, stream, x, hA, n);

    int gbA = (total + 512 * IPTA - 1) / (512 * IPTA);   // 391
    hipLaunchKernelGGL(k_win, dim3(gbA), dim3(512), 0, stream,
                       orders, total, epo, NW, gcnt1, recs1, ovfcnts + 0, ovf1);

    hipLaunchKernelGGL(k_bsort, dim3(NW), dim3(512), 0, stream,
                       edge_i, ne, gcnt1, recs1, NW, NBD, K2, recs2, boffs);

    float* cur = hA; float* nxt = hB;
    for (int s = 0; s < n_orders; ++s) {
        bool fin = (s == n_orders - 1);
        if (fin) {
            hipLaunchKernelGGL((k_agg3<true>), dim3(NBD), dim3(512), 0, stream,
                               cur, nxt, boffs, recs2, NW, K2, NBD, s,
                               w_mp, b_mp, w_out, b_out, out, n,
                               ovfcnts + 1, ovf2);
            hipLaunchKernelGGL(k_fix_final, dim3(8), dim3(256), 0, stream,
                               cur, out, edge_i, ne,
                               ovfcnts + 0, ovf1, ovfcnts + 1, ovf2,
                               w_mp, b_mp, w_out, s);
        } else {
            hipLaunchKernelGGL((k_agg3<false>), dim3(NBD), dim3(512), 0, stream,
                               cur, nxt, boffs, recs2, NW, K2, NBD, s,
                               w_mp, b_mp, w_out, b_out, out, n,
                               ovfcnts + 1, ovf2);
            hipLaunchKernelGGL(k_fix, dim3(8), dim3(256), 0, stream,
                               cur, nxt, edge_i, ne,
                               ovfcnts + 0, ovf1, ovfcnts + 1, ovf2,
                               w_mp, b_mp, s);
            float* t2 = cur; cur = nxt; nxt = t2;
        }
    }
}